// Round 16
// baseline (119.432 us; speedup 1.0000x reference)
//
#include <hip/hip_runtime.h>

#define DEVINL __device__ __forceinline__

typedef __attribute__((ext_vector_type(4))) float f32x4;
typedef __attribute__((ext_vector_type(8))) short short8;

constexpr int kBN = 12, kC = 256, kH = 40, kW = 100;
constexpr int kNQ = kH * kW;      // 4000
constexpr int kM = kBN * kNQ;     // 48000

DEVINL float bflo(uint p) { union { uint i; float f; } v; v.i = p << 16; return v.f; }
DEVINL float bfhi(uint p) { union { uint i; float f; } v; v.i = p & 0xffff0000u; return v.f; }
DEVINL ushort f2bf(float f) {
  union { float f; uint i; } v; v.f = f;
  uint i = v.i;
  return (ushort)((i + 0x7fffu + ((i >> 16) & 1u)) >> 16);  // RNE
}
DEVINL uint pack2(float a, float b) { return (uint)f2bf(a) | ((uint)f2bf(b) << 16); }

DEVINL void mfma_bf16(f32x4& acc, short8 a, short8 b) {
  acc = __builtin_amdgcn_mfma_f32_16x16x32_bf16(a, b, acc, 0, 0, 0);
}

DEVINL void gload16(const ushort* g, char* lds) {
  __builtin_amdgcn_global_load_lds(
      (const __attribute__((address_space(1))) uint*)g,
      (__attribute__((address_space(3))) uint*)lds, 16, 0, 0);
}

DEVINL void acc8(float* acc, uint4 d, float wv) {
  acc[0] += wv * bflo(d.x); acc[1] += wv * bfhi(d.x);
  acc[2] += wv * bflo(d.y); acc[3] += wv * bfhi(d.y);
  acc[4] += wv * bflo(d.z); acc[5] += wv * bfhi(d.z);
  acc[6] += wv * bflo(d.w); acc[7] += wv * bfhi(d.w);
}

// ---------------- K1: img transpose (blocks 0..3023) + weight prep (3024+) --
__global__ __launch_bounds__(256) void k_prep(const float* __restrict__ img,
                                              ushort* __restrict__ feat,
                                              const float* __restrict__ Wv,
                                              const float* __restrict__ Woff,
                                              const float* __restrict__ Wattn,
                                              const float* __restrict__ Wout,
                                              ushort* __restrict__ WvT,
                                              ushort* __restrict__ WoffT,
                                              ushort* __restrict__ WattnT,
                                              ushort* __restrict__ WoutT) {
  __shared__ ushort tile[64][66];
  int bx = blockIdx.x, t = threadIdx.x;
  if (bx < 3024) {
    int qb = bx % 63, cb = (bx / 63) & 3, b = bx / 252;
    int c0 = cb * 64, q0 = qb * 64;
    int ql = t & 63, cl = t >> 6;
#pragma unroll
    for (int i = 0; i < 16; ++i) {
      int c = cl + i * 4, q = q0 + ql;
      float v = (q < kNQ) ? img[(size_t)(b * kC + c0 + c) * kNQ + q] : 0.f;
      tile[c][ql] = f2bf(v);
    }
    __syncthreads();
#pragma unroll
    for (int i = 0; i < 2; ++i) {
      int idx = t + i * 256;
      int qlo = idx >> 3, cg = idx & 7;
      int q = q0 + qlo;
      if (q < kNQ) {
        ushort tmp[8];
#pragma unroll
        for (int j = 0; j < 8; ++j) tmp[j] = tile[cg * 8 + j][qlo];
        *(uint4*)(feat + ((size_t)b * kNQ + q) * kC + c0 + cg * 8) = *(uint4*)tmp;
      }
    }
  } else {
    int idx = (bx - 3024) * 256 + t;
    const float* W; ushort* WT; int N, base;
    if (idx < 65536)       { W = Wv;    WT = WvT;    N = 256; base = 0; }
    else if (idx < 81920)  { W = Woff;  WT = WoffT;  N = 64;  base = 65536; }
    else if (idx < 90112)  { W = Wattn; WT = WattnT; N = 32;  base = 81920; }
    else if (idx < 155648) { W = Wout;  WT = WoutT;  N = 256; base = 90112; }
    else return;
    int i = idx - base;
    int n = i >> 8, k = i & 255;
    WT[i] = f2bf(W[k * N + n]);
  }
}

// ---------------- K2: MERGED warp (blocks 756..6755) + offattn (0..755) ------
// samp layout: [b][h][q][p] packed 12 B {sx, sy, w}
__global__ __launch_bounds__(256) void k_warp_offattn(const ushort* __restrict__ feat,
                                                      const float* __restrict__ grid,
                                                      ushort* __restrict__ warped,
                                                      const ushort* __restrict__ WoffT,
                                                      const ushort* __restrict__ WattnT,
                                                      const float* __restrict__ boff,
                                                      const float* __restrict__ battn,
                                                      const float* __restrict__ refp,
                                                      float* __restrict__ samp) {
  extern __shared__ char smem[];
  const int t = threadIdx.x;
  int bx = blockIdx.x;

  if (bx >= 756) {
    // ---------------- warp path ----------------
    int orig = bx - 756;
    int n = (orig & 7) * 750 + (orig >> 3);   // bijective, 6000 = 8*750
    int ql = t >> 5, g = t & 31;              // 8 q per block, 32 lanes per q
    int gq = n * 8 + ql;
    int b = gq / kNQ;
    float gx = grid[(size_t)gq * 2 + 0] * kW - 0.5f;
    float gy = grid[(size_t)gq * 2 + 1] * kH - 0.5f;
    float x0f = floorf(gx), y0f = floorf(gy);
    int x0 = (int)x0f, y0 = (int)y0f;
    float wx = gx - x0f, wy = gy - y0f;
    float acc[8];
#pragma unroll
    for (int i = 0; i < 8; ++i) acc[i] = 0.f;
    const ushort* fb = feat + (size_t)b * kNQ * kC + g * 8;
#pragma unroll
    for (int ty = 0; ty < 2; ++ty) {
      int iy = y0 + ty;
      if (iy < 0 || iy >= kH) continue;
      float wyv = ty ? wy : 1.f - wy;
#pragma unroll
      for (int tx = 0; tx < 2; ++tx) {
        int ix = x0 + tx;
        if (ix < 0 || ix >= kW) continue;
        float wv = wyv * (tx ? wx : 1.f - wx);
        uint4 d = *(const uint4*)(fb + (size_t)(iy * kW + ix) * kC);
        acc8(acc, d, wv);
      }
    }
    uint o[4] = {pack2(acc[0], acc[1]), pack2(acc[2], acc[3]),
                 pack2(acc[4], acc[5]), pack2(acc[6], acc[7])};
    *(uint4*)(warped + (size_t)gq * kC + g * 8) = *(uint4*)o;
    return;
  }

  // ---------------- offattn path (counted-vmcnt dbuf GEMM + softmax) --------
  float* T = (float*)smem;    // epilogue [64][101] fp32 (aliases staging bufs)
  const int wave = t >> 6, lane = t & 63;
  const int l15 = lane & 15, l4 = lane >> 4;
  const int b = bx / 63, mb = bx % 63;
  const int q0 = mb * 64;
  const int nrows = (kNQ - q0 < 64) ? (kNQ - q0) : 64;
  const int wr = wave >> 1, wc = wave & 1;
  const int ra = t >> 2, ca = t & 3;
  const int rac = (ra < nrows) ? ra : (nrows - 1);
  const int sca = ca ^ ((ra >> 1) & 3);
  const ushort* gA  = feat + ((size_t)b * kNQ + q0 + rac) * 256 + sca * 8;
  const ushort* gB0 = WoffT + (size_t)ra * 256 + sca * 8;
  const ushort* gB1 = WattnT + (size_t)ra * 256 + sca * 8;  // t<128 (ra<32)

  f32x4 acc[2][3];
#pragma unroll
  for (int i = 0; i < 2; ++i)
#pragma unroll
    for (int j = 0; j < 3; ++j) acc[i][j] = (f32x4)0.f;

  auto STAGE = [&](int buf, int kk) {
    char* Asb = smem + buf * 10240;
    char* Bsb = Asb + 4096;
    gload16(gA + kk, Asb + t * 16);
    gload16(gB0 + kk, Bsb + t * 16);
    if (t < 128) gload16(gB1 + kk, Bsb + (256 + t) * 16);
  };

  STAGE(0, 0);
  int cur = 0;
#pragma unroll 1
  for (int step = 0; step < 8; ++step) {
    if (step < 7) {
      STAGE(cur ^ 1, (step + 1) * 32);
      if (wave < 2) asm volatile("s_waitcnt vmcnt(3)" ::: "memory");
      else          asm volatile("s_waitcnt vmcnt(2)" ::: "memory");
    } else {
      asm volatile("s_waitcnt vmcnt(0)" ::: "memory");
    }
    __builtin_amdgcn_s_barrier();
    asm volatile("" ::: "memory");
    char* Asb = smem + cur * 10240;
    char* Bsb = Asb + 4096;
    short8 af[2], bf[3];
#pragma unroll
    for (int mf = 0; mf < 2; ++mf) {
      int r = wr * 32 + mf * 16 + l15;
      int sl = l4 ^ ((r >> 1) & 3);
      af[mf] = *(const short8*)(Asb + r * 64 + sl * 16);
    }
#pragma unroll
    for (int nf = 0; nf < 3; ++nf) {
      int r = wc * 48 + nf * 16 + l15;
      int sl = l4 ^ ((r >> 1) & 3);
      bf[nf] = *(const short8*)(Bsb + r * 64 + sl * 16);
    }
#pragma unroll
    for (int mf = 0; mf < 2; ++mf)
#pragma unroll
      for (int nf = 0; nf < 3; ++nf) mfma_bf16(acc[mf][nf], af[mf], bf[nf]);
    asm volatile("" ::: "memory");
    __builtin_amdgcn_s_barrier();
    cur ^= 1;
  }

#pragma unroll
  for (int nf = 0; nf < 3; ++nf) {
    int col = wc * 48 + nf * 16 + l15;
    float bv = (col < 64) ? boff[col] : battn[col - 64];
#pragma unroll
    for (int mf = 0; mf < 2; ++mf)
#pragma unroll
      for (int j = 0; j < 4; ++j) {
        int row = wr * 32 + mf * 16 + l4 * 4 + j;
        T[row * 101 + col] = acc[mf][nf][j] + bv;
      }
  }
  __syncthreads();
  int row = t >> 2;
  if (row < nrows) {
    int q = q0 + row;
    float refx = refp[((size_t)b * kNQ + q) * 2 + 0] * kW - 0.5f;
    float refy = refp[((size_t)b * kNQ + q) * 2 + 1] * kH - 0.5f;
#pragma unroll
    for (int hi2 = 0; hi2 < 2; ++hi2) {
      int h = (t & 3) + hi2 * 4;
      float sx[4], sy[4], lg[4];
#pragma unroll
      for (int p = 0; p < 4; ++p) {
        sx[p] = refx + T[row * 101 + h * 8 + p * 2 + 0];
        sy[p] = refy + T[row * 101 + h * 8 + p * 2 + 1];
        lg[p] = T[row * 101 + 64 + h * 4 + p];
      }
      float mx = fmaxf(fmaxf(lg[0], lg[1]), fmaxf(lg[2], lg[3]));
      float e[4], s = 0.f;
#pragma unroll
      for (int p = 0; p < 4; ++p) { e[p] = __expf(lg[p] - mx); s += e[p]; }
      float inv = 1.f / s;
      float* dst = samp + (((size_t)(b * 8 + h) * kNQ + q) * 4) * 3;
#pragma unroll
      for (int p = 0; p < 4; ++p) {
        dst[p * 3 + 0] = sx[p];
        dst[p * 3 + 1] = sy[p];
        dst[p * 3 + 2] = e[p] * inv;
      }
    }
  }
}

// ---------------- K3/K5: MFMA GEMM v5: BM=128, BN=256, BK=32, 512 thr -------
// 8 waves (2M x 4N), wave = 64x64 (4x4 frags). Counted-vmcnt dbuf: 3 uniform
// loads/thread/step (A 1 + B 2) -> vmcnt(3). LDS 2 x 24576 B.
// EPI 0: v head-major bf16 [b][h][q][32]; EPI 1: NCHW fp32 + bf16 resid(feat).
template <int EPI>
__global__ __launch_bounds__(512) void k_gemm128(const ushort* __restrict__ A,
                                                 const ushort* __restrict__ BT,
                                                 const float* __restrict__ bias,
                                                 ushort* __restrict__ Obf,
                                                 float* __restrict__ Ofp,
                                                 const ushort* __restrict__ feat) {
  extern __shared__ char smem[];
  const int t = threadIdx.x, wave = t >> 6, lane = t & 63;
  const int l15 = lane & 15, l4 = lane >> 4;
  const int b = blockIdx.x >> 5, mb = blockIdx.x & 31;   // 12 x 32 grid
  const int q0 = mb * 128;
  const int nrows = (kNQ - q0 < 128) ? (kNQ - q0) : 128;  // 128 or 32 (mb=31)
  const int wr = wave >> 2, wc = wave & 3;                // 2M x 4N
  const int ra = t >> 2, ca = t & 3;                      // A: 128 rows x 4 chunks
  const int rac = (ra < nrows) ? ra : (nrows - 1);        // clamp: uniform loads
  const int sca = ca ^ ((ra >> 1) & 3);
  const ushort* gA = A + ((size_t)b * kNQ + q0 + rac) * 256 + sca * 8;
  const ushort* gB = BT + (size_t)ra * 256 + sca * 8;     // rows ra, ra+128

  f32x4 acc[4][4];
#pragma unroll
  for (int i = 0; i < 4; ++i)
#pragma unroll
    for (int j = 0; j < 4; ++j) acc[i][j] = (f32x4)0.f;

  auto STAGE = [&](int buf, int kk) {
    char* Asb = smem + buf * 24576;           // [128][64B] = 8192 B
    char* Bsb = Asb + 8192;                   // [256][64B] = 16384 B
    gload16(gA + kk, Asb + t * 16);
#pragma unroll
    for (int i = 0; i < 2; ++i)
      gload16(gB + (size_t)i * 128 * 256 + kk, Bsb + (i * 512 + t) * 16);
  };

  STAGE(0, 0);
  int cur = 0;
#pragma unroll 1
  for (int step = 0; step < 8; ++step) {
    if (step < 7) {
      STAGE(cur ^ 1, (step + 1) * 32);
      asm volatile("s_waitcnt vmcnt(3)" ::: "memory");
    } else {
      asm volatile("s_waitcnt vmcnt(0)" ::: "memory");
    }
    __builtin_amdgcn_s_barrier();
    asm volatile("" ::: "memory");
    char* Asb = smem + cur * 24576;
    char* Bsb = Asb + 8192;
    short8 af[4], bf[4];
#pragma unroll
    for (int mf = 0; mf < 4; ++mf) {
      int r = wr * 64 + mf * 16 + l15;
      int sl = l4 ^ ((r >> 1) & 3);
      af[mf] = *(const short8*)(Asb + r * 64 + sl * 16);
    }
#pragma unroll
    for (int nf = 0; nf < 4; ++nf) {
      int r = wc * 64 + nf * 16 + l15;
      int sl = l4 ^ ((r >> 1) & 3);
      bf[nf] = *(const short8*)(Bsb + r * 64 + sl * 16);
    }
#pragma unroll
    for (int mf = 0; mf < 4; ++mf)
#pragma unroll
      for (int nf = 0; nf < 4; ++nf) mfma_bf16(acc[mf][nf], af[mf], bf[nf]);
    asm volatile("" ::: "memory");
    __builtin_amdgcn_s_barrier();
    cur ^= 1;
  }

  if (EPI == 0) {
#pragma unroll
    for (int mf = 0; mf < 4; ++mf) {
      int rl = wr * 64 + mf * 16;
      if (rl >= nrows) continue;
      int q = q0 + rl + l4 * 4;
#pragma unroll
      for (int nf = 0; nf < 4; ++nf) {
        int col = wc * 64 + nf * 16 + l15;
        float bv = bias[col];
        int h = col >> 5, ch = col & 31;
        ushort* dst = Obf + (size_t)(b * 8 + h) * kNQ * 32 + ch;
#pragma unroll
        for (int j = 0; j < 4; ++j)
          dst[(size_t)(q + j) * 32] = f2bf(acc[mf][nf][j] + bv);
      }
    }
  } else {
    // per-wave transpose scratch: [16 cols][68 rows] fp32 = 4352 B per wave
    float* Tw = (float*)(smem + wave * 4352);
#pragma unroll
    for (int nf = 0; nf < 4; ++nf) {
      float bv = bias[wc * 64 + nf * 16 + l15];
#pragma unroll
      for (int mf = 0; mf < 4; ++mf)
#pragma unroll
        for (int j = 0; j < 4; ++j)
          Tw[l15 * 68 + mf * 16 + l4 * 4 + j] = acc[mf][nf][j] + bv;
      int c = l15, rs = l4 * 16;             // rs within wave's 64-row range
      if (wr * 64 + rs < nrows) {
        int col = wc * 64 + nf * 16 + c;
        size_t grow = (size_t)q0 + wr * 64 + rs;
        size_t gi = ((size_t)b * kC + col) * kNQ + grow;
        const ushort* fr = feat + ((size_t)b * kNQ + grow) * kC + col;
#pragma unroll
        for (int k = 0; k < 4; ++k) {
          float4 tv = *(float4*)(&Tw[c * 68 + rs + k * 4]);
          tv.x += bflo(fr[(size_t)(k * 4 + 0) * kC]);
          tv.y += bflo(fr[(size_t)(k * 4 + 1) * kC]);
          tv.z += bflo(fr[(size_t)(k * 4 + 2) * kC]);
          tv.w += bflo(fr[(size_t)(k * 4 + 3) * kC]);
          *(float4*)(Ofp + gi + k * 4) = tv;
        }
      }
    }
  }
}

// ---------------- K4: deformable sampling + attention aggregate --------------
__global__ __launch_bounds__(256) void k_sample(const ushort* __restrict__ v,
                                                const float* __restrict__ samp,
                                                ushort* __restrict__ agg) {
  int orig = blockIdx.x;
  int n = (orig & 7) * 756 + (orig >> 3);      // bijective, 6048 = 8*756
  int plane = n / 63, chunk = n - plane * 63;  // 96 planes x 63 chunks
  int t = threadIdx.x;
  int ql = t >> 2, g = t & 3;                  // 64 q per block, 4 lanes per q
  int q = chunk * 64 + ql;
  if (q >= kNQ) return;
  int b = plane >> 3, h = plane & 7;
  const ushort* pv = v + (size_t)plane * kNQ * 32 + g * 8;
  const int lane = t & 63, gbase = lane & ~3;

  const float* sp = samp + (((size_t)plane * kNQ + q) * 4 + g) * 3;
  float myx = sp[0], myy = sp[1], myw = sp[2];   // lane g owns point g
  float acc[8];
#pragma unroll
  for (int i = 0; i < 8; ++i) acc[i] = 0.f;
#pragma unroll
  for (int p = 0; p < 4; ++p) {
    float sxp = __shfl(myx, gbase + p);
    float syp = __shfl(myy, gbase + p);
    float wp  = __shfl(myw, gbase + p);
    float x0f = floorf(sxp), y0f = floorf(syp);
    int x0 = (int)x0f, y0 = (int)y0f;
    float wx = sxp - x0f, wy = syp - y0f;
#pragma unroll
    for (int ty = 0; ty < 2; ++ty) {
      int iy = y0 + ty;
      if (iy < 0 || iy >= kH) continue;
      float wyv = ty ? wy : 1.f - wy;
#pragma unroll
      for (int tx = 0; tx < 2; ++tx) {
        int ix = x0 + tx;
        if (ix < 0 || ix >= kW) continue;
        float wv = wp * wyv * (tx ? wx : 1.f - wx);
        uint4 d = *(const uint4*)(pv + (size_t)(iy * kW + ix) * 32);
        acc8(acc, d, wv);
      }
    }
  }
  uint o[4] = {pack2(acc[0], acc[1]), pack2(acc[2], acc[3]),
               pack2(acc[4], acc[5]), pack2(acc[6], acc[7])};
  *(uint4*)(agg + ((size_t)b * kNQ + q) * kC + h * 32 + g * 8) = *(uint4*)o;
}

extern "C" void kernel_launch(void* const* d_in, const int* in_sizes, int n_in,
                              void* d_out, int out_size, void* d_ws, size_t ws_size,
                              hipStream_t stream) {
  const float* img   = (const float*)d_in[0];
  const float* grid  = (const float*)d_in[1];
  const float* refp  = (const float*)d_in[2];
  const float* Wv    = (const float*)d_in[3];
  const float* bv    = (const float*)d_in[4];
  const float* Woff  = (const float*)d_in[5];
  const float* boff  = (const float*)d_in[6];
  const float* Wattn = (const float*)d_in[7];
  const float* battn = (const float*)d_in[8];
  const float* Wout  = (const float*)d_in[9];
  const float* bout  = (const float*)d_in[10];
  float* out = (float*)d_out;

  char* ws = (char*)d_ws;
  const size_t SZ = (size_t)kM * kC * 2;  // 24.576 MB per bf16 [M][C] buffer
  ushort* feat   = (ushort*)(ws);
  ushort* warped = (ushort*)(ws + SZ);
  ushort* vbuf   = (ushort*)(ws + 2 * SZ);           // [b][h][q][32] head-major
  float*  samp   = (float*)(ws + 3 * SZ);            // [b][h][q][p]{x,y,w} 18.4 MB
  ushort* WvT    = (ushort*)(ws + 4 * SZ);
  ushort* WoffT  = (ushort*)(ws + 4 * SZ + 131072);
  ushort* WattnT = (ushort*)(ws + 4 * SZ + 131072 + 32768);
  ushort* WoutT  = (ushort*)(ws + 4 * SZ + 131072 + 32768 + 16384);
  ushort* aggb   = warped;  // warped is dead after gemmv; reuse for agg

  k_prep<<<3632, 256, 0, stream>>>(img, feat, Wv, Woff, Wattn, Wout,
                                   WvT, WoffT, WattnT, WoutT);
  k_warp_offattn<<<6756, 256, 25856, stream>>>(feat, grid, warped, WoffT, WattnT,
                                               boff, battn, refp, samp);
  k_gemm128<0><<<384, 512, 49152, stream>>>(warped, WvT, bv, vbuf, nullptr, nullptr);
  k_sample<<<6048, 256, 0, stream>>>(vbuf, samp, aggb);
  k_gemm128<1><<<384, 512, 49152, stream>>>(aggb, WoutT, bout, nullptr, out, feat);
}

// Round 17
// 115.214 us; speedup vs baseline: 1.0366x; 1.0366x over previous
//
#include <hip/hip_runtime.h>

#define DEVINL __device__ __forceinline__

typedef __attribute__((ext_vector_type(4))) float f32x4;
typedef __attribute__((ext_vector_type(8))) short short8;

constexpr int kBN = 12, kC = 256, kH = 40, kW = 100;
constexpr int kNQ = kH * kW;      // 4000
constexpr int kM = kBN * kNQ;     // 48000

DEVINL float bflo(uint p) { union { uint i; float f; } v; v.i = p << 16; return v.f; }
DEVINL float bfhi(uint p) { union { uint i; float f; } v; v.i = p & 0xffff0000u; return v.f; }
DEVINL ushort f2bf(float f) {
  union { float f; uint i; } v; v.f = f;
  uint i = v.i;
  return (ushort)((i + 0x7fffu + ((i >> 16) & 1u)) >> 16);  // RNE
}
DEVINL uint pack2(float a, float b) { return (uint)f2bf(a) | ((uint)f2bf(b) << 16); }

DEVINL void mfma_bf16(f32x4& acc, short8 a, short8 b) {
  acc = __builtin_amdgcn_mfma_f32_16x16x32_bf16(a, b, acc, 0, 0, 0);
}

DEVINL void gload16(const ushort* g, char* lds) {
  __builtin_amdgcn_global_load_lds(
      (const __attribute__((address_space(1))) uint*)g,
      (__attribute__((address_space(3))) uint*)lds, 16, 0, 0);
}

DEVINL void acc8(float* acc, uint4 d, float wv) {
  acc[0] += wv * bflo(d.x); acc[1] += wv * bfhi(d.x);
  acc[2] += wv * bflo(d.y); acc[3] += wv * bfhi(d.y);
  acc[4] += wv * bflo(d.z); acc[5] += wv * bfhi(d.z);
  acc[6] += wv * bflo(d.w); acc[7] += wv * bfhi(d.w);
}

// ---------------- K1: img transpose (blocks 0..3023) + weight prep (3024+) --
__global__ __launch_bounds__(256) void k_prep(const float* __restrict__ img,
                                              ushort* __restrict__ feat,
                                              const float* __restrict__ Wv,
                                              const float* __restrict__ Woff,
                                              const float* __restrict__ Wattn,
                                              const float* __restrict__ Wout,
                                              ushort* __restrict__ WvT,
                                              ushort* __restrict__ WoffT,
                                              ushort* __restrict__ WattnT,
                                              ushort* __restrict__ WoutT) {
  __shared__ ushort tile[64][66];
  int bx = blockIdx.x, t = threadIdx.x;
  if (bx < 3024) {
    int qb = bx % 63, cb = (bx / 63) & 3, b = bx / 252;
    int c0 = cb * 64, q0 = qb * 64;
    int ql = t & 63, cl = t >> 6;
#pragma unroll
    for (int i = 0; i < 16; ++i) {
      int c = cl + i * 4, q = q0 + ql;
      float v = (q < kNQ) ? img[(size_t)(b * kC + c0 + c) * kNQ + q] : 0.f;
      tile[c][ql] = f2bf(v);
    }
    __syncthreads();
#pragma unroll
    for (int i = 0; i < 2; ++i) {
      int idx = t + i * 256;
      int qlo = idx >> 3, cg = idx & 7;
      int q = q0 + qlo;
      if (q < kNQ) {
        ushort tmp[8];
#pragma unroll
        for (int j = 0; j < 8; ++j) tmp[j] = tile[cg * 8 + j][qlo];
        *(uint4*)(feat + ((size_t)b * kNQ + q) * kC + c0 + cg * 8) = *(uint4*)tmp;
      }
    }
  } else {
    int idx = (bx - 3024) * 256 + t;
    const float* W; ushort* WT; int N, base;
    if (idx < 65536)       { W = Wv;    WT = WvT;    N = 256; base = 0; }
    else if (idx < 81920)  { W = Woff;  WT = WoffT;  N = 64;  base = 65536; }
    else if (idx < 90112)  { W = Wattn; WT = WattnT; N = 32;  base = 81920; }
    else if (idx < 155648) { W = Wout;  WT = WoutT;  N = 256; base = 90112; }
    else return;
    int i = idx - base;
    int n = i >> 8, k = i & 255;
    WT[i] = f2bf(W[k * N + n]);
  }
}

// ---------------- K2: MERGED warp (blocks 756..6755) + offattn (0..755) ------
// samp layout: [b][h][q][p] packed 12 B {sx, sy, w}
__global__ __launch_bounds__(256) void k_warp_offattn(const ushort* __restrict__ feat,
                                                      const float* __restrict__ grid,
                                                      ushort* __restrict__ warped,
                                                      const ushort* __restrict__ WoffT,
                                                      const ushort* __restrict__ WattnT,
                                                      const float* __restrict__ boff,
                                                      const float* __restrict__ battn,
                                                      const float* __restrict__ refp,
                                                      float* __restrict__ samp) {
  extern __shared__ char smem[];
  const int t = threadIdx.x;
  int bx = blockIdx.x;

  if (bx >= 756) {
    // ---------------- warp path ----------------
    int orig = bx - 756;
    int n = (orig & 7) * 750 + (orig >> 3);   // bijective, 6000 = 8*750
    int ql = t >> 5, g = t & 31;              // 8 q per block, 32 lanes per q
    int gq = n * 8 + ql;
    int b = gq / kNQ;
    float2 gv = *(const float2*)(grid + (size_t)gq * 2);
    float gx = gv.x * kW - 0.5f;
    float gy = gv.y * kH - 0.5f;
    float x0f = floorf(gx), y0f = floorf(gy);
    int x0 = (int)x0f, y0 = (int)y0f;
    float wx = gx - x0f, wy = gy - y0f;
    float acc[8];
#pragma unroll
    for (int i = 0; i < 8; ++i) acc[i] = 0.f;
    const ushort* fb = feat + (size_t)b * kNQ * kC + g * 8;
#pragma unroll
    for (int ty = 0; ty < 2; ++ty) {
      int iy = y0 + ty;
      if (iy < 0 || iy >= kH) continue;
      float wyv = ty ? wy : 1.f - wy;
#pragma unroll
      for (int tx = 0; tx < 2; ++tx) {
        int ix = x0 + tx;
        if (ix < 0 || ix >= kW) continue;
        float wv = wyv * (tx ? wx : 1.f - wx);
        uint4 d = *(const uint4*)(fb + (size_t)(iy * kW + ix) * kC);
        acc8(acc, d, wv);
      }
    }
    uint o[4] = {pack2(acc[0], acc[1]), pack2(acc[2], acc[3]),
                 pack2(acc[4], acc[5]), pack2(acc[6], acc[7])};
    *(uint4*)(warped + (size_t)gq * kC + g * 8) = *(uint4*)o;
    return;
  }

  // ---------------- offattn path (counted-vmcnt dbuf GEMM + softmax) --------
  float* T = (float*)smem;    // epilogue [64][101] fp32 (aliases staging bufs)
  const int wave = t >> 6, lane = t & 63;
  const int l15 = lane & 15, l4 = lane >> 4;
  const int b = bx / 63, mb = bx % 63;
  const int q0 = mb * 64;
  const int nrows = (kNQ - q0 < 64) ? (kNQ - q0) : 64;
  const int wr = wave >> 1, wc = wave & 1;
  const int ra = t >> 2, ca = t & 3;
  const int rac = (ra < nrows) ? ra : (nrows - 1);
  const int sca = ca ^ ((ra >> 1) & 3);
  const ushort* gA  = feat + ((size_t)b * kNQ + q0 + rac) * 256 + sca * 8;
  const ushort* gB0 = WoffT + (size_t)ra * 256 + sca * 8;
  const ushort* gB1 = WattnT + (size_t)ra * 256 + sca * 8;  // t<128 (ra<32)

  f32x4 acc[2][3];
#pragma unroll
  for (int i = 0; i < 2; ++i)
#pragma unroll
    for (int j = 0; j < 3; ++j) acc[i][j] = (f32x4)0.f;

  auto STAGE = [&](int buf, int kk) {
    char* Asb = smem + buf * 10240;
    char* Bsb = Asb + 4096;
    gload16(gA + kk, Asb + t * 16);
    gload16(gB0 + kk, Bsb + t * 16);
    if (t < 128) gload16(gB1 + kk, Bsb + (256 + t) * 16);
  };

  STAGE(0, 0);
  int cur = 0;
#pragma unroll 1
  for (int step = 0; step < 8; ++step) {
    if (step < 7) {
      STAGE(cur ^ 1, (step + 1) * 32);
      if (wave < 2) asm volatile("s_waitcnt vmcnt(3)" ::: "memory");
      else          asm volatile("s_waitcnt vmcnt(2)" ::: "memory");
    } else {
      asm volatile("s_waitcnt vmcnt(0)" ::: "memory");
    }
    __builtin_amdgcn_s_barrier();
    asm volatile("" ::: "memory");
    char* Asb = smem + cur * 10240;
    char* Bsb = Asb + 4096;
    short8 af[2], bf[3];
#pragma unroll
    for (int mf = 0; mf < 2; ++mf) {
      int r = wr * 32 + mf * 16 + l15;
      int sl = l4 ^ ((r >> 1) & 3);
      af[mf] = *(const short8*)(Asb + r * 64 + sl * 16);
    }
#pragma unroll
    for (int nf = 0; nf < 3; ++nf) {
      int r = wc * 48 + nf * 16 + l15;
      int sl = l4 ^ ((r >> 1) & 3);
      bf[nf] = *(const short8*)(Bsb + r * 64 + sl * 16);
    }
#pragma unroll
    for (int mf = 0; mf < 2; ++mf)
#pragma unroll
      for (int nf = 0; nf < 3; ++nf) mfma_bf16(acc[mf][nf], af[mf], bf[nf]);
    asm volatile("" ::: "memory");
    __builtin_amdgcn_s_barrier();
    cur ^= 1;
  }

#pragma unroll
  for (int nf = 0; nf < 3; ++nf) {
    int col = wc * 48 + nf * 16 + l15;
    float bv = (col < 64) ? boff[col] : battn[col - 64];
#pragma unroll
    for (int mf = 0; mf < 2; ++mf)
#pragma unroll
      for (int j = 0; j < 4; ++j) {
        int row = wr * 32 + mf * 16 + l4 * 4 + j;
        T[row * 101 + col] = acc[mf][nf][j] + bv;
      }
  }
  __syncthreads();
  int row = t >> 2;
  if (row < nrows) {
    int q = q0 + row;
    float2 rv = *(const float2*)(refp + ((size_t)b * kNQ + q) * 2);
    float refx = rv.x * kW - 0.5f;
    float refy = rv.y * kH - 0.5f;
#pragma unroll
    for (int hi2 = 0; hi2 < 2; ++hi2) {
      int h = (t & 3) + hi2 * 4;
      float sx[4], sy[4], lg[4];
#pragma unroll
      for (int p = 0; p < 4; ++p) {
        sx[p] = refx + T[row * 101 + h * 8 + p * 2 + 0];
        sy[p] = refy + T[row * 101 + h * 8 + p * 2 + 1];
        lg[p] = T[row * 101 + 64 + h * 4 + p];
      }
      float mx = fmaxf(fmaxf(lg[0], lg[1]), fmaxf(lg[2], lg[3]));
      float e[4], s = 0.f;
#pragma unroll
      for (int p = 0; p < 4; ++p) { e[p] = __expf(lg[p] - mx); s += e[p]; }
      float inv = 1.f / s;
      float* dst = samp + (((size_t)(b * 8 + h) * kNQ + q) * 4) * 3;
#pragma unroll
      for (int p = 0; p < 4; ++p) {
        dst[p * 3 + 0] = sx[p];
        dst[p * 3 + 1] = sy[p];
        dst[p * 3 + 2] = e[p] * inv;
      }
    }
  }
}

// ---------------- K3: MFMA GEMM v (BM=64, BN=256), counted-vmcnt dbuf --------
__global__ __launch_bounds__(256) void k_gemmv(const ushort* __restrict__ A,
                                               const ushort* __restrict__ BT,
                                               const float* __restrict__ bias,
                                               ushort* __restrict__ Obf) {
  extern __shared__ char smem[];
  const int t = threadIdx.x, wave = t >> 6, lane = t & 63;
  const int l15 = lane & 15, l4 = lane >> 4;
  const int b = blockIdx.x / 63, mb = blockIdx.x % 63;
  const int q0 = mb * 64;
  const int nrows = (kNQ - q0 < 64) ? (kNQ - q0) : 64;
  const int n0w = wave * 64;
  const int ra = t >> 2, ca = t & 3;
  const int rac = (ra < nrows) ? ra : (nrows - 1);
  const int sca = ca ^ ((ra >> 1) & 3);
  const ushort* gA = A + ((size_t)b * kNQ + q0 + rac) * 256 + sca * 8;
  const ushort* gB = BT + (size_t)ra * 256 + sca * 8;

  f32x4 acc[4][4];
#pragma unroll
  for (int i = 0; i < 4; ++i)
#pragma unroll
    for (int j = 0; j < 4; ++j) acc[i][j] = (f32x4)0.f;

  auto STAGE = [&](int buf, int kk) {
    char* Asb = smem + buf * 20480;
    char* Bsb = Asb + 4096;
    gload16(gA + kk, Asb + t * 16);
#pragma unroll
    for (int i = 0; i < 4; ++i)
      gload16(gB + (size_t)i * 64 * 256 + kk, Bsb + (i * 256 + t) * 16);
  };

  STAGE(0, 0);
  int cur = 0;
#pragma unroll 1
  for (int step = 0; step < 8; ++step) {
    if (step < 7) {
      STAGE(cur ^ 1, (step + 1) * 32);
      asm volatile("s_waitcnt vmcnt(5)" ::: "memory");
    } else {
      asm volatile("s_waitcnt vmcnt(0)" ::: "memory");
    }
    __builtin_amdgcn_s_barrier();
    asm volatile("" ::: "memory");
    char* Asb = smem + cur * 20480;
    char* Bsb = Asb + 4096;
    short8 af[4], bf[4];
#pragma unroll
    for (int mf = 0; mf < 4; ++mf) {
      int r = mf * 16 + l15;
      int sl = l4 ^ ((r >> 1) & 3);
      af[mf] = *(const short8*)(Asb + r * 64 + sl * 16);
    }
#pragma unroll
    for (int nf = 0; nf < 4; ++nf) {
      int r = n0w + nf * 16 + l15;
      int sl = l4 ^ ((r >> 1) & 3);
      bf[nf] = *(const short8*)(Bsb + r * 64 + sl * 16);
    }
#pragma unroll
    for (int mf = 0; mf < 4; ++mf)
#pragma unroll
      for (int nf = 0; nf < 4; ++nf) mfma_bf16(acc[mf][nf], af[mf], bf[nf]);
    asm volatile("" ::: "memory");
    __builtin_amdgcn_s_barrier();
    cur ^= 1;
  }

#pragma unroll
  for (int mf = 0; mf < 4; ++mf) {
    if (mf * 16 >= nrows) continue;
    int q = q0 + mf * 16 + l4 * 4;
#pragma unroll
    for (int nf = 0; nf < 4; ++nf) {
      int col = n0w + nf * 16 + l15;
      float bv = bias[col];
      int h = col >> 5, ch = col & 31;
      ushort* dst = Obf + (size_t)(b * 8 + h) * kNQ * 32 + ch;
#pragma unroll
      for (int j = 0; j < 4; ++j)
        dst[(size_t)(q + j) * 32] = f2bf(acc[mf][nf][j] + bv);
    }
  }
}

// ---------------- K4: deformable sampling + attention aggregate --------------
__global__ __launch_bounds__(256) void k_sample(const ushort* __restrict__ v,
                                                const float* __restrict__ samp,
                                                ushort* __restrict__ agg) {
  int orig = blockIdx.x;
  int n = (orig & 7) * 756 + (orig >> 3);      // bijective, 6048 = 8*756
  int plane = n / 63, chunk = n - plane * 63;  // 96 planes x 63 chunks
  int t = threadIdx.x;
  int ql = t >> 2, g = t & 3;                  // 64 q per block, 4 lanes per q
  int q = chunk * 64 + ql;
  if (q >= kNQ) return;
  int b = plane >> 3, h = plane & 7;
  const ushort* pv = v + (size_t)plane * kNQ * 32 + g * 8;
  const int lane = t & 63, gbase = lane & ~3;

  const float* sp = samp + (((size_t)plane * kNQ + q) * 4 + g) * 3;
  float myx = sp[0], myy = sp[1], myw = sp[2];   // lane g owns point g
  float acc[8];
#pragma unroll
  for (int i = 0; i < 8; ++i) acc[i] = 0.f;
#pragma unroll
  for (int p = 0; p < 4; ++p) {
    float sxp = __shfl(myx, gbase + p);
    float syp = __shfl(myy, gbase + p);
    float wp  = __shfl(myw, gbase + p);
    float x0f = floorf(sxp), y0f = floorf(syp);
    int x0 = (int)x0f, y0 = (int)y0f;
    float wx = sxp - x0f, wy = syp - y0f;
#pragma unroll
    for (int ty = 0; ty < 2; ++ty) {
      int iy = y0 + ty;
      if (iy < 0 || iy >= kH) continue;
      float wyv = ty ? wy : 1.f - wy;
#pragma unroll
      for (int tx = 0; tx < 2; ++tx) {
        int ix = x0 + tx;
        if (ix < 0 || ix >= kW) continue;
        float wv = wp * wyv * (tx ? wx : 1.f - wx);
        uint4 d = *(const uint4*)(pv + (size_t)(iy * kW + ix) * 32);
        acc8(acc, d, wv);
      }
    }
  }
  uint o[4] = {pack2(acc[0], acc[1]), pack2(acc[2], acc[3]),
               pack2(acc[4], acc[5]), pack2(acc[6], acc[7])};
  *(uint4*)(agg + ((size_t)b * kNQ + q) * kC + h * 32 + g * 8) = *(uint4*)o;
}

// ---------------- K5: MFMA GEMM out, bf16 residual from feat -----------------
__global__ __launch_bounds__(256) void k_gemmout(const ushort* __restrict__ A,
                                                 const ushort* __restrict__ BT,
                                                 const float* __restrict__ bias,
                                                 float* __restrict__ Ofp,
                                                 const ushort* __restrict__ feat) {
  extern __shared__ char smem[];
  const int t = threadIdx.x, wave = t >> 6, lane = t & 63;
  const int l15 = lane & 15, l4 = lane >> 4;
  const int b = blockIdx.x / 63, mb = blockIdx.x % 63;
  const int q0 = mb * 64;
  const int nrows = (kNQ - q0 < 64) ? (kNQ - q0) : 64;
  const int n0w = wave * 64;
  const int ra = t >> 2, ca = t & 3;
  const int rac = (ra < nrows) ? ra : (nrows - 1);
  const int sca = ca ^ ((ra >> 1) & 3);
  const ushort* gA = A + ((size_t)b * kNQ + q0 + rac) * 256 + sca * 8;
  const ushort* gB = BT + (size_t)ra * 256 + sca * 8;

  f32x4 acc[4][4];
#pragma unroll
  for (int i = 0; i < 4; ++i)
#pragma unroll
    for (int j = 0; j < 4; ++j) acc[i][j] = (f32x4)0.f;

  auto STAGE = [&](int buf, int kk) {
    char* Asb = smem + buf * 20480;
    char* Bsb = Asb + 4096;
    gload16(gA + kk, Asb + t * 16);
#pragma unroll
    for (int i = 0; i < 4; ++i)
      gload16(gB + (size_t)i * 64 * 256 + kk, Bsb + (i * 256 + t) * 16);
  };

  STAGE(0, 0);
  int cur = 0;
#pragma unroll 1
  for (int step = 0; step < 8; ++step) {
    if (step < 7) {
      STAGE(cur ^ 1, (step + 1) * 32);
      asm volatile("s_waitcnt vmcnt(5)" ::: "memory");
    } else {
      asm volatile("s_waitcnt vmcnt(0)" ::: "memory");
    }
    __builtin_amdgcn_s_barrier();
    asm volatile("" ::: "memory");
    char* Asb = smem + cur * 20480;
    char* Bsb = Asb + 4096;
    short8 af[4], bf[4];
#pragma unroll
    for (int mf = 0; mf < 4; ++mf) {
      int r = mf * 16 + l15;
      int sl = l4 ^ ((r >> 1) & 3);
      af[mf] = *(const short8*)(Asb + r * 64 + sl * 16);
    }
#pragma unroll
    for (int nf = 0; nf < 4; ++nf) {
      int r = n0w + nf * 16 + l15;
      int sl = l4 ^ ((r >> 1) & 3);
      bf[nf] = *(const short8*)(Bsb + r * 64 + sl * 16);
    }
#pragma unroll
    for (int mf = 0; mf < 4; ++mf)
#pragma unroll
      for (int nf = 0; nf < 4; ++nf) mfma_bf16(acc[mf][nf], af[mf], bf[nf]);
    asm volatile("" ::: "memory");
    __builtin_amdgcn_s_barrier();
    cur ^= 1;
  }

  // epilogue: per-wave LDS transpose + bf16 residual (from feat) + NCHW store
  float* Tw = (float*)(smem + wave * 4352);   // [16 cols][68 rows] fp32
#pragma unroll
  for (int nf = 0; nf < 4; ++nf) {
    float bv = bias[n0w + nf * 16 + l15];
#pragma unroll
    for (int mf = 0; mf < 4; ++mf)
#pragma unroll
      for (int j = 0; j < 4; ++j)
        Tw[l15 * 68 + mf * 16 + l4 * 4 + j] = acc[mf][nf][j] + bv;
    int c = l15, rs = l4 * 16;
    if (rs < nrows) {
      int col = n0w + nf * 16 + c;
      size_t gi = ((size_t)b * kC + col) * kNQ + q0 + rs;
      const ushort* fr = feat + ((size_t)b * kNQ + q0 + rs) * kC + col;
#pragma unroll
      for (int k = 0; k < 4; ++k) {
        float4 tv = *(float4*)(&Tw[c * 68 + rs + k * 4]);
        tv.x += bflo(fr[(size_t)(k * 4 + 0) * kC]);
        tv.y += bflo(fr[(size_t)(k * 4 + 1) * kC]);
        tv.z += bflo(fr[(size_t)(k * 4 + 2) * kC]);
        tv.w += bflo(fr[(size_t)(k * 4 + 3) * kC]);
        *(float4*)(Ofp + gi + k * 4) = tv;
      }
    }
  }
}

extern "C" void kernel_launch(void* const* d_in, const int* in_sizes, int n_in,
                              void* d_out, int out_size, void* d_ws, size_t ws_size,
                              hipStream_t stream) {
  const float* img   = (const float*)d_in[0];
  const float* grid  = (const float*)d_in[1];
  const float* refp  = (const float*)d_in[2];
  const float* Wv    = (const float*)d_in[3];
  const float* bv    = (const float*)d_in[4];
  const float* Woff  = (const float*)d_in[5];
  const float* boff  = (const float*)d_in[6];
  const float* Wattn = (const float*)d_in[7];
  const float* battn = (const float*)d_in[8];
  const float* Wout  = (const float*)d_in[9];
  const float* bout  = (const float*)d_in[10];
  float* out = (float*)d_out;

  char* ws = (char*)d_ws;
  const size_t SZ = (size_t)kM * kC * 2;  // 24.576 MB per bf16 [M][C] buffer
  ushort* feat   = (ushort*)(ws);
  ushort* warped = (ushort*)(ws + SZ);
  ushort* vbuf   = (ushort*)(ws + 2 * SZ);           // [b][h][q][32] head-major
  float*  samp   = (float*)(ws + 3 * SZ);            // [b][h][q][p]{x,y,w} 18.4 MB
  ushort* WvT    = (ushort*)(ws + 4 * SZ);
  ushort* WoffT  = (ushort*)(ws + 4 * SZ + 131072);
  ushort* WattnT = (ushort*)(ws + 4 * SZ + 131072 + 32768);
  ushort* WoutT  = (ushort*)(ws + 4 * SZ + 131072 + 32768 + 16384);
  ushort* aggb   = warped;  // warped is dead after gemmv; reuse for agg

  k_prep<<<3632, 256, 0, stream>>>(img, feat, Wv, Woff, Wattn, Wout,
                                   WvT, WoffT, WattnT, WoutT);
  k_warp_offattn<<<6756, 256, 25856, stream>>>(feat, grid, warped, WoffT, WattnT,
                                               boff, battn, refp, samp);
  k_gemmv<<<756, 256, 40960, stream>>>(warped, WvT, bv, vbuf);
  k_sample<<<6048, 256, 0, stream>>>(vbuf, samp, aggb);
  k_gemmout<<<756, 256, 40960, stream>>>(aggb, WoutT, bout, out, feat);
}